// Round 11
// baseline (73.534 us; speedup 1.0000x reference)
//
#include <hip/hip_runtime.h>

#define BATCH 16
#define TOK   4096
#define DIM   768
#define SMAX  128
#define BM    4     // segments (= MLP rows) per block

__device__ __forceinline__ int lower_bound_i(const int* __restrict__ a, int n, int v) {
    int lo = 0, hi = n;
    while (lo < hi) {
        int m = (lo + hi) >> 1;
        if (a[m] < v) lo = m + 1; else hi = m;
    }
    return lo;
}

__device__ __forceinline__ float f4get(const float4& v, int k) {
    switch (k) {
        case 0: return v.x;
        case 1: return v.y;
        case 2: return v.z;
        default: return v.w;
    }
}

__device__ __forceinline__ void f2acc(float2& a, const float2& v) {
    a.x += v.x; a.y += v.y;
}

// Kernel 0: precompute span boundaries (independent parallel searches).
__global__ __launch_bounds__(192)
void bounds_kernel(const int* __restrict__ seg, int* __restrict__ bounds) {
    const int b = blockIdx.x;
    const int s = threadIdx.x;
    if (s <= SMAX)
        bounds[b * (SMAX + 1) + s] = lower_bound_i(seg + b * TOK, TOK, s);
}

// Fused kernel, BM=4, grid=512 -> 2 blocks/CU for phaseA(HBM)/phaseB(VALU)
// overlap. LDS exactly 80 KB; launch_bounds(1024,8) caps VGPR at 64.
// Phase A: 8 groups x 128 lanes; segment sg's span is mid-split between
// groups 2sg (first half) and 2sg+1 (second half); halves combined at
// layer-1 read. Phase B: k-split MLP, weights read once per block.
__global__ __launch_bounds__(1024, 8)
void fused_kernel(const float* __restrict__ hidden,
                  const int* __restrict__ bounds,
                  const float* __restrict__ W1, const float* __restrict__ b1,
                  const float* __restrict__ W2, const float* __restrict__ b2,
                  const float* __restrict__ W3, const float* __restrict__ b3,
                  float* __restrict__ out) {
    __shared__ __align__(16) float A2[2 * BM * DIM];    // 24 KB (half-span partials)
    __shared__ __align__(16) float P [8 * BM * 384];    // 48 KB
    __shared__ __align__(16) float X1[BM * 384];        //  6 KB
    __shared__ __align__(16) float X2[BM * 128];        //  2 KB

    const int tid  = threadIdx.x;
    const int row0 = blockIdx.x * BM;
    const int b    = row0 / SMAX;
    const int s0   = row0 % SMAX;

    // ================= phase A: half-span segment sums -> A2 =================
    {
        const int grp  = tid >> 7;        // 0..7
        const int lane = tid & 127;       // owns 6 floats: cols lane*6..+6
        const int sg   = grp >> 1;        // segment 0..3 within block
        const int ph   = grp & 1;         // half 0/1

        const int lo  = bounds[b * (SMAX + 1) + s0 + sg];
        const int hi  = bounds[b * (SMAX + 1) + s0 + sg + 1];
        const int mid = (lo + hi) >> 1;
        const int t0  = ph ? mid : lo;
        const int t1  = ph ? hi  : mid;

        const float2* __restrict__ hp =
            reinterpret_cast<const float2*>(hidden + (size_t)b * TOK * DIM) + lane * 3;

        float2 a0 = make_float2(0.f, 0.f);
        float2 a1 = make_float2(0.f, 0.f);
        float2 a2 = make_float2(0.f, 0.f);

        int t = t0;
        for (; t + 4 <= t1; t += 4) {
            float2 v0[4], v1[4], v2[4];
            #pragma unroll
            for (int u = 0; u < 4; ++u) {
                const float2* p = hp + (size_t)(t + u) * 384;
                v0[u] = p[0]; v1[u] = p[1]; v2[u] = p[2];
            }
            #pragma unroll
            for (int u = 0; u < 4; ++u) {
                f2acc(a0, v0[u]); f2acc(a1, v1[u]); f2acc(a2, v2[u]);
            }
        }
        for (; t < t1; ++t) {
            const float2* p = hp + (size_t)t * 384;
            f2acc(a0, p[0]); f2acc(a1, p[1]); f2acc(a2, p[2]);
        }

        float2* dA = reinterpret_cast<float2*>(&A2[(ph * BM + sg) * DIM + lane * 6]);
        dA[0] = a0; dA[1] = a1; dA[2] = a2;
    }
    __syncthreads();

    // ================= phase B: k-split MLP =================
    const int c1 = tid & 127;   // weight column within 128-group
    const int kg = tid >> 7;    // k-slice group 0..7

    // ---- layer 1: cols {c1,+128,+256}, rows 0..3, k in [kg*96, kg*96+96) ----
    {
        float acc[BM][3];
        #pragma unroll
        for (int r = 0; r < BM; ++r)
            #pragma unroll
            for (int j = 0; j < 3; ++j) acc[r][j] = 0.f;

        const int k0 = kg * 96;
        for (int k = k0; k < k0 + 96; k += 4) {
            float4 a[BM];
            #pragma unroll
            for (int r = 0; r < BM; ++r) {
                const float4 u = *reinterpret_cast<const float4*>(&A2[r * DIM + k]);
                const float4 v = *reinterpret_cast<const float4*>(&A2[(BM + r) * DIM + k]);
                a[r] = make_float4(u.x + v.x, u.y + v.y, u.z + v.z, u.w + v.w);
            }
            #pragma unroll
            for (int kk = 0; kk < 4; ++kk) {
                const float w0 = W1[(size_t)(k + kk) * 384 + c1];
                const float w1 = W1[(size_t)(k + kk) * 384 + c1 + 128];
                const float w2 = W1[(size_t)(k + kk) * 384 + c1 + 256];
                #pragma unroll
                for (int r = 0; r < BM; ++r) {
                    const float av = f4get(a[r], kk);
                    acc[r][0] = fmaf(av, w0, acc[r][0]);
                    acc[r][1] = fmaf(av, w1, acc[r][1]);
                    acc[r][2] = fmaf(av, w2, acc[r][2]);
                }
            }
        }
        #pragma unroll
        for (int r = 0; r < BM; ++r)
            #pragma unroll
            for (int j = 0; j < 3; ++j)
                P[(kg * BM + r) * 384 + c1 + j * 128] = acc[r][j];
    }
    __syncthreads();

    // ---- reduce partials -> X1 (bias + relu), 1536 outputs ----
    for (int i = tid; i < BM * 384; i += 1024) {
        const int row = i / 384;
        const int col = i - row * 384;
        float s = b1[col];
        #pragma unroll
        for (int g = 0; g < 8; ++g)
            s += P[(g * BM + row) * 384 + col];
        X1[i] = s > 0.f ? s : 0.f;
    }
    __syncthreads();

    // ---- layer 2: col c1, rows 0..3, k in [kg*48, kg*48+48) ----
    {
        float acc2[BM];
        #pragma unroll
        for (int r = 0; r < BM; ++r) acc2[r] = 0.f;

        const int k0 = kg * 48;
        for (int k = k0; k < k0 + 48; k += 4) {
            float4 x[BM];
            #pragma unroll
            for (int r = 0; r < BM; ++r)
                x[r] = *reinterpret_cast<const float4*>(&X1[r * 384 + k]);
            #pragma unroll
            for (int kk = 0; kk < 4; ++kk) {
                const float w = W2[(size_t)(k + kk) * 128 + c1];
                #pragma unroll
                for (int r = 0; r < BM; ++r)
                    acc2[r] = fmaf(f4get(x[r], kk), w, acc2[r]);
            }
        }
        #pragma unroll
        for (int r = 0; r < BM; ++r)
            P[(kg * BM + r) * 128 + c1] = acc2[r];
    }
    __syncthreads();

    // ---- reduce partials -> X2 (bias + relu), 512 outputs ----
    if (tid < BM * 128) {
        const int row = tid >> 7;
        const int col = c1;
        float s = b2[col];
        #pragma unroll
        for (int g = 0; g < 8; ++g)
            s += P[(g * BM + row) * 128 + col];
        X2[row * 128 + col] = s > 0.f ? s : 0.f;
    }
    __syncthreads();

    // ---- layer 3: BM*2 = 8 outputs ----
    if (tid < BM * 2) {
        const int r = tid >> 1;
        const int c = tid & 1;
        float sacc = 0.f;
        #pragma unroll 8
        for (int k = 0; k < 128; ++k)
            sacc = fmaf(X2[r * 128 + k], W3[k * 2 + c], sacc);
        out[(row0 + r) * 2 + c] = sacc + b3[c];
    }
}

extern "C" void kernel_launch(void* const* d_in, const int* in_sizes, int n_in,
                              void* d_out, int out_size, void* d_ws, size_t ws_size,
                              hipStream_t stream) {
    const float* hidden = (const float*)d_in[0];
    const int*   seg    = (const int*)d_in[1];
    const float* W1     = (const float*)d_in[2];
    const float* b1     = (const float*)d_in[3];
    const float* W2     = (const float*)d_in[4];
    const float* b2     = (const float*)d_in[5];
    const float* W3     = (const float*)d_in[6];
    const float* b3     = (const float*)d_in[7];
    float* out  = (float*)d_out;
    int* bounds = (int*)d_ws;   // 16*129*4 = 8.3 KB, ws is ample

    bounds_kernel<<<BATCH, 192, 0, stream>>>(seg, bounds);
    fused_kernel<<<(BATCH * SMAX) / BM, 1024, 0, stream>>>(
        hidden, bounds, W1, b1, W2, b2, W3, b3, out);
}

// Round 12
// 72.239 us; speedup vs baseline: 1.0179x; 1.0179x over previous
//
#include <hip/hip_runtime.h>

#define BATCH 16
#define TOK   4096
#define DIM   768
#define SMAX  128
#define BM    4     // segments (= MLP rows) per block

__device__ __forceinline__ int lower_bound_i(const int* __restrict__ a, int n, int v) {
    int lo = 0, hi = n;
    while (lo < hi) {
        int m = (lo + hi) >> 1;
        if (a[m] < v) lo = m + 1; else hi = m;
    }
    return lo;
}

__device__ __forceinline__ float f4get(const float4& v, int k) {
    switch (k) {
        case 0: return v.x;
        case 1: return v.y;
        case 2: return v.z;
        default: return v.w;
    }
}

__device__ __forceinline__ void f2acc(float2& a, const float2& v) {
    a.x += v.x; a.y += v.y;
}

// Kernel 0: precompute span boundaries (independent parallel searches).
__global__ __launch_bounds__(192)
void bounds_kernel(const int* __restrict__ seg, int* __restrict__ bounds) {
    const int b = blockIdx.x;
    const int s = threadIdx.x;
    if (s <= SMAX)
        bounds[b * (SMAX + 1) + s] = lower_bound_i(seg + b * TOK, TOK, s);
}

// Fused kernel: BM=4, 512 threads (8 waves), LDS 44 KB, VGPR cap 128 via
// launch_bounds(512,4) -> 2 blocks/CU. One resident block streams phase A
// (HBM/L3) while the other computes phase B (VALU) -> cross-block overlap
// without the R11 VGPR-32 spill disaster.
__global__ __launch_bounds__(512, 4)
void fused_kernel(const float* __restrict__ hidden,
                  const int* __restrict__ bounds,
                  const float* __restrict__ W1, const float* __restrict__ b1,
                  const float* __restrict__ W2, const float* __restrict__ b2,
                  const float* __restrict__ W3, const float* __restrict__ b3,
                  float* __restrict__ out) {
    __shared__ __align__(16) float A [BM * DIM];        // 12 KB
    __shared__ __align__(16) float P [4 * BM * 384];    // 24 KB (reused for layer2)
    __shared__ __align__(16) float X1[BM * 384];        //  6 KB
    __shared__ __align__(16) float X2[BM * 128];        //  2 KB

    const int tid  = threadIdx.x;
    const int row0 = blockIdx.x * BM;
    const int b    = row0 / SMAX;
    const int s0   = row0 % SMAX;

    const int grp  = tid >> 7;    // 0..3
    const int lane = tid & 127;

    // ================= phase A: segment sums -> A =================
    {
        const int lo = bounds[b * (SMAX + 1) + s0 + grp];
        const int hi = bounds[b * (SMAX + 1) + s0 + grp + 1];

        // float2 view: row has 384 float2; this thread owns 3 at lane*3
        const float2* __restrict__ hp =
            reinterpret_cast<const float2*>(hidden + (size_t)b * TOK * DIM) + lane * 3;

        float2 a0 = make_float2(0.f, 0.f);
        float2 a1 = make_float2(0.f, 0.f);
        float2 a2 = make_float2(0.f, 0.f);

        int t = lo;
        for (; t + 4 <= hi; t += 4) {
            float2 v0[4], v1[4], v2[4];
            #pragma unroll
            for (int u = 0; u < 4; ++u) {
                const float2* p = hp + (size_t)(t + u) * 384;
                v0[u] = p[0]; v1[u] = p[1]; v2[u] = p[2];
            }
            #pragma unroll
            for (int u = 0; u < 4; ++u) {
                f2acc(a0, v0[u]); f2acc(a1, v1[u]); f2acc(a2, v2[u]);
            }
        }
        for (; t < hi; ++t) {
            const float2* p = hp + (size_t)t * 384;
            f2acc(a0, p[0]); f2acc(a1, p[1]); f2acc(a2, p[2]);
        }

        float2* dA = reinterpret_cast<float2*>(&A[grp * DIM + lane * 6]);
        dA[0] = a0; dA[1] = a1; dA[2] = a2;
    }
    __syncthreads();

    // ================= phase B: k-split MLP =================
    const int c1 = lane;          // weight column within 128-group
    const int kg = grp;           // k-slice group 0..3

    // ---- layer 1: cols {c1,+128,+256}, rows 0..3, k in [kg*192, +192) ----
    {
        float acc[BM][3];
        #pragma unroll
        for (int r = 0; r < BM; ++r)
            #pragma unroll
            for (int j = 0; j < 3; ++j) acc[r][j] = 0.f;

        const int k0 = kg * 192;
        for (int k = k0; k < k0 + 192; k += 4) {
            float4 a[BM];
            #pragma unroll
            for (int r = 0; r < BM; ++r)
                a[r] = *reinterpret_cast<const float4*>(&A[r * DIM + k]);
            #pragma unroll
            for (int kk = 0; kk < 4; ++kk) {
                const float w0 = W1[(size_t)(k + kk) * 384 + c1];
                const float w1 = W1[(size_t)(k + kk) * 384 + c1 + 128];
                const float w2 = W1[(size_t)(k + kk) * 384 + c1 + 256];
                #pragma unroll
                for (int r = 0; r < BM; ++r) {
                    const float av = f4get(a[r], kk);
                    acc[r][0] = fmaf(av, w0, acc[r][0]);
                    acc[r][1] = fmaf(av, w1, acc[r][1]);
                    acc[r][2] = fmaf(av, w2, acc[r][2]);
                }
            }
        }
        #pragma unroll
        for (int r = 0; r < BM; ++r)
            #pragma unroll
            for (int j = 0; j < 3; ++j)
                P[(kg * BM + r) * 384 + c1 + j * 128] = acc[r][j];
    }
    __syncthreads();

    // ---- reduce partials -> X1 (bias + relu), 1536 outputs ----
    for (int i = tid; i < BM * 384; i += 512) {
        const int row = i / 384;
        const int col = i - row * 384;
        float s = b1[col];
        #pragma unroll
        for (int g = 0; g < 4; ++g)
            s += P[(g * BM + row) * 384 + col];
        X1[i] = s > 0.f ? s : 0.f;
    }
    __syncthreads();

    // ---- layer 2: col c1, rows 0..3, k in [kg*96, +96) ----
    {
        float acc2[BM];
        #pragma unroll
        for (int r = 0; r < BM; ++r) acc2[r] = 0.f;

        const int k0 = kg * 96;
        for (int k = k0; k < k0 + 96; k += 4) {
            float4 x[BM];
            #pragma unroll
            for (int r = 0; r < BM; ++r)
                x[r] = *reinterpret_cast<const float4*>(&X1[r * 384 + k]);
            #pragma unroll
            for (int kk = 0; kk < 4; ++kk) {
                const float w = W2[(size_t)(k + kk) * 128 + c1];
                #pragma unroll
                for (int r = 0; r < BM; ++r)
                    acc2[r] = fmaf(f4get(x[r], kk), w, acc2[r]);
            }
        }
        #pragma unroll
        for (int r = 0; r < BM; ++r)
            P[(kg * BM + r) * 128 + c1] = acc2[r];
    }
    __syncthreads();

    // ---- reduce partials -> X2 (bias + relu), 512 outputs (1/thread) ----
    {
        const int row = grp;
        const int col = c1;
        float s = b2[col];
        #pragma unroll
        for (int g = 0; g < 4; ++g)
            s += P[(g * BM + row) * 128 + col];
        X2[row * 128 + col] = s > 0.f ? s : 0.f;
    }
    __syncthreads();

    // ---- layer 3: BM*2 = 8 outputs ----
    if (tid < BM * 2) {
        const int r = tid >> 1;
        const int c = tid & 1;
        float sacc = 0.f;
        #pragma unroll 8
        for (int k = 0; k < 128; ++k)
            sacc = fmaf(X2[r * 128 + k], W3[k * 2 + c], sacc);
        out[(row0 + r) * 2 + c] = sacc + b3[c];
    }
}

extern "C" void kernel_launch(void* const* d_in, const int* in_sizes, int n_in,
                              void* d_out, int out_size, void* d_ws, size_t ws_size,
                              hipStream_t stream) {
    const float* hidden = (const float*)d_in[0];
    const int*   seg    = (const int*)d_in[1];
    const float* W1     = (const float*)d_in[2];
    const float* b1     = (const float*)d_in[3];
    const float* W2     = (const float*)d_in[4];
    const float* b2     = (const float*)d_in[5];
    const float* W3     = (const float*)d_in[6];
    const float* b3     = (const float*)d_in[7];
    float* out  = (float*)d_out;
    int* bounds = (int*)d_ws;   // 16*129*4 = 8.3 KB, ws is ample

    bounds_kernel<<<BATCH, 192, 0, stream>>>(seg, bounds);
    fused_kernel<<<(BATCH * SMAX) / BM, 512, 0, stream>>>(
        hidden, bounds, W1, b1, W2, b2, W3, b3, out);
}

// Round 13
// 70.696 us; speedup vs baseline: 1.0401x; 1.0218x over previous
//
#include <hip/hip_runtime.h>

#define BATCH 16
#define TOK   4096
#define DIM   768
#define SMAX  128
#define BM    8     // segments (= MLP rows) per block

__device__ __forceinline__ int lower_bound_i(const int* __restrict__ a, int n, int v) {
    int lo = 0, hi = n;
    while (lo < hi) {
        int m = (lo + hi) >> 1;
        if (a[m] < v) lo = m + 1; else hi = m;
    }
    return lo;
}

__device__ __forceinline__ float f4get(const float4& v, int k) {
    switch (k) {
        case 0: return v.x;
        case 1: return v.y;
        case 2: return v.z;
        default: return v.w;
    }
}

__device__ __forceinline__ void f2acc(float2& a, const float2& v) {
    a.x += v.x; a.y += v.y;
}

// Kernel 0: precompute span boundaries (independent parallel searches).
__global__ __launch_bounds__(192)
void bounds_kernel(const int* __restrict__ seg, int* __restrict__ bounds) {
    const int b = blockIdx.x;
    const int s = threadIdx.x;
    if (s <= SMAX)
        bounds[b * (SMAX + 1) + s] = lower_bound_i(seg + b * TOK, TOK, s);
}

// Fused kernel (R10 structure + phase-A token balancing).
// Phase A: block's whole token range [bounds[s0], bounds[s0+8]) split EVENLY
// across 8 groups (128 lanes each). Each group walks its sub-range; full-inside
// segment runs write A[s] directly (exclusive); boundary runs go to per-group
// partial slots (Apart, aliased into P) and are combined in fixed g-order.
// Deterministic, no atomics. Phase B: k-split MLP identical to R10.
__global__ __launch_bounds__(1024)
void fused_kernel(const float* __restrict__ hidden,
                  const int* __restrict__ bounds,
                  const float* __restrict__ W1, const float* __restrict__ b1,
                  const float* __restrict__ W2, const float* __restrict__ b2,
                  const float* __restrict__ W3, const float* __restrict__ b3,
                  float* __restrict__ out) {
    __shared__ __align__(16) float A [BM * DIM];        // 24 KB
    __shared__ __align__(16) float X1[BM * 384];        // 12 KB
    __shared__ __align__(16) float X2[BM * 128];        //  4 KB
    __shared__ __align__(16) float P [8 * BM * 384];    // 96 KB (phase A: Apart alias)
    __shared__ int sbounds[BM + 1];
    __shared__ int fseg[8], lseg[8];

    float* Apart = P;   // [16][DIM] = 48 KB, dead before phase B writes P

    const int tid  = threadIdx.x;
    const int row0 = blockIdx.x * BM;
    const int b    = row0 / SMAX;
    const int s0   = row0 % SMAX;
    const int grp  = tid >> 7;    // 0..7
    const int lane = tid & 127;   // owns cols lane*6 .. lane*6+5 (3 float2)

    if (tid <= BM) sbounds[tid] = bounds[b * (SMAX + 1) + s0 + tid];
    if (tid < 8) { fseg[tid] = -1; lseg[tid] = -1; }
    for (int i = tid; i < BM * DIM; i += 1024) A[i] = 0.f;
    __syncthreads();

    // ================= phase A: balanced segment sums =================
    {
        const int L = sbounds[0], H = sbounds[BM];
        const int total = H - L;
        const int t0 = L + ((total * grp) >> 3);
        const int t1 = L + ((total * (grp + 1)) >> 3);

        const float2* __restrict__ hp =
            reinterpret_cast<const float2*>(hidden + (size_t)b * TOK * DIM) + lane * 3;

        if (t0 < t1) {
            int curs = 0;
            while (sbounds[curs + 1] <= t0) ++curs;   // segment containing t0
            const int sfirst = curs;
            int t = t0;
            while (t < t1) {
                while (sbounds[curs + 1] <= t) ++curs;   // skip empty segments
                const int send = min(t1, sbounds[curs + 1]);

                float2 r0 = make_float2(0.f, 0.f);
                float2 r1 = make_float2(0.f, 0.f);
                float2 r2 = make_float2(0.f, 0.f);
                for (; t + 4 <= send; t += 4) {
                    float2 v0[4], v1[4], v2[4];
                    #pragma unroll
                    for (int u = 0; u < 4; ++u) {
                        const float2* p = hp + (size_t)(t + u) * (DIM / 2);
                        v0[u] = p[0]; v1[u] = p[1]; v2[u] = p[2];
                    }
                    #pragma unroll
                    for (int u = 0; u < 4; ++u) {
                        f2acc(r0, v0[u]); f2acc(r1, v1[u]); f2acc(r2, v2[u]);
                    }
                }
                for (; t < send; ++t) {
                    const float2* p = hp + (size_t)t * (DIM / 2);
                    f2acc(r0, p[0]); f2acc(r1, p[1]); f2acc(r2, p[2]);
                }

                float2* dst;
                if (curs == sfirst) {                       // left-boundary run
                    dst = reinterpret_cast<float2*>(&Apart[(grp * 2 + 0) * DIM]) + lane * 3;
                    if (lane == 0) fseg[grp] = curs;
                } else if (sbounds[curs + 1] > t1) {        // right-boundary run
                    dst = reinterpret_cast<float2*>(&Apart[(grp * 2 + 1) * DIM]) + lane * 3;
                    if (lane == 0) lseg[grp] = curs;
                } else {                                     // interior: exclusive
                    dst = reinterpret_cast<float2*>(&A[curs * DIM]) + lane * 3;
                }
                dst[0] = r0; dst[1] = r1; dst[2] = r2;
            }
        }
    }
    __syncthreads();

    // ---- combine boundary partials into A (fixed order -> deterministic) ----
    for (int i = tid; i < BM * DIM; i += 1024) {
        const int r = i / DIM;
        const int col = i - r * DIM;
        float v = A[i];
        #pragma unroll
        for (int g = 0; g < 8; ++g) {
            if (fseg[g] == r) v += Apart[(g * 2 + 0) * DIM + col];
            if (lseg[g] == r) v += Apart[(g * 2 + 1) * DIM + col];
        }
        A[i] = v;
    }
    __syncthreads();

    // ================= phase B: k-split MLP (identical to R10) =================
    const int c1 = lane;          // weight column within 128-group
    const int kg = grp;           // k-slice group 0..7

    // ---- layer 1: cols {c1,+128,+256}, rows 0..7, k in [kg*96, kg*96+96) ----
    {
        float acc[BM][3];
        #pragma unroll
        for (int r = 0; r < BM; ++r)
            #pragma unroll
            for (int j = 0; j < 3; ++j) acc[r][j] = 0.f;

        const int k0 = kg * 96;
        for (int k = k0; k < k0 + 96; k += 4) {
            float4 a[BM];
            #pragma unroll
            for (int r = 0; r < BM; ++r)
                a[r] = *reinterpret_cast<const float4*>(&A[r * DIM + k]);
            #pragma unroll
            for (int kk = 0; kk < 4; ++kk) {
                const float w0 = W1[(size_t)(k + kk) * 384 + c1];
                const float w1 = W1[(size_t)(k + kk) * 384 + c1 + 128];
                const float w2 = W1[(size_t)(k + kk) * 384 + c1 + 256];
                #pragma unroll
                for (int r = 0; r < BM; ++r) {
                    const float av = f4get(a[r], kk);
                    acc[r][0] = fmaf(av, w0, acc[r][0]);
                    acc[r][1] = fmaf(av, w1, acc[r][1]);
                    acc[r][2] = fmaf(av, w2, acc[r][2]);
                }
            }
        }
        #pragma unroll
        for (int r = 0; r < BM; ++r)
            #pragma unroll
            for (int j = 0; j < 3; ++j)
                P[(kg * BM + r) * 384 + c1 + j * 128] = acc[r][j];
    }
    __syncthreads();

    // ---- reduce partials -> X1 (bias + relu) ----
    for (int i = tid; i < BM * 384; i += 1024) {
        const int row = i / 384;
        const int col = i - row * 384;
        float s = b1[col];
        #pragma unroll
        for (int g = 0; g < 8; ++g)
            s += P[(g * BM + row) * 384 + col];
        X1[i] = s > 0.f ? s : 0.f;
    }
    __syncthreads();

    // ---- layer 2: col c1, rows 0..7, k in [kg*48, kg*48+48) ----
    {
        float acc2[BM];
        #pragma unroll
        for (int r = 0; r < BM; ++r) acc2[r] = 0.f;

        const int k0 = kg * 48;
        for (int k = k0; k < k0 + 48; k += 4) {
            float4 x[BM];
            #pragma unroll
            for (int r = 0; r < BM; ++r)
                x[r] = *reinterpret_cast<const float4*>(&X1[r * 384 + k]);
            #pragma unroll
            for (int kk = 0; kk < 4; ++kk) {
                const float w = W2[(size_t)(k + kk) * 128 + c1];
                #pragma unroll
                for (int r = 0; r < BM; ++r)
                    acc2[r] = fmaf(f4get(x[r], kk), w, acc2[r]);
            }
        }
        #pragma unroll
        for (int r = 0; r < BM; ++r)
            P[(kg * BM + r) * 128 + c1] = acc2[r];
    }
    __syncthreads();

    // ---- reduce partials -> X2 (bias + relu) ----
    {
        const int row = grp;
        const int col = c1;
        float s = b2[col];
        #pragma unroll
        for (int g = 0; g < 8; ++g)
            s += P[(g * BM + row) * 128 + col];
        X2[row * 128 + col] = s > 0.f ? s : 0.f;
    }
    __syncthreads();

    // ---- layer 3: 16 outputs ----
    if (tid < BM * 2) {
        const int r = tid >> 1;
        const int c = tid & 1;
        float sacc = 0.f;
        #pragma unroll 8
        for (int k = 0; k < 128; ++k)
            sacc = fmaf(X2[r * 128 + k], W3[k * 2 + c], sacc);
        out[(row0 + r) * 2 + c] = sacc + b3[c];
    }
}

extern "C" void kernel_launch(void* const* d_in, const int* in_sizes, int n_in,
                              void* d_out, int out_size, void* d_ws, size_t ws_size,
                              hipStream_t stream) {
    const float* hidden = (const float*)d_in[0];
    const int*   seg    = (const int*)d_in[1];
    const float* W1     = (const float*)d_in[2];
    const float* b1     = (const float*)d_in[3];
    const float* W2     = (const float*)d_in[4];
    const float* b2     = (const float*)d_in[5];
    const float* W3     = (const float*)d_in[6];
    const float* b3     = (const float*)d_in[7];
    float* out  = (float*)d_out;
    int* bounds = (int*)d_ws;   // 16*129*4 = 8.3 KB, ws is ample

    bounds_kernel<<<BATCH, 192, 0, stream>>>(seg, bounds);
    fused_kernel<<<(BATCH * SMAX) / BM, 1024, 0, stream>>>(
        hidden, bounds, W1, b1, W2, b2, W3, b3, out);
}

// Round 14
// 66.021 us; speedup vs baseline: 1.1138x; 1.0708x over previous
//
#include <hip/hip_runtime.h>

#define BATCH 16
#define TOK   4096
#define DIM   768
#define SMAX  128
#define BM    8     // segments (= MLP rows) per block

typedef float f32x4 __attribute__((ext_vector_type(4)));
typedef short s16x8 __attribute__((ext_vector_type(8)));

__device__ __forceinline__ int lower_bound_i(const int* __restrict__ a, int n, int v) {
    int lo = 0, hi = n;
    while (lo < hi) {
        int m = (lo + hi) >> 1;
        if (a[m] < v) lo = m + 1; else hi = m;
    }
    return lo;
}

__device__ __forceinline__ float f4get(const float4& v, int k) {
    switch (k) {
        case 0: return v.x;
        case 1: return v.y;
        case 2: return v.z;
        default: return v.w;
    }
}

__device__ __forceinline__ void f2acc(float2& a, const float2& v) {
    a.x += v.x; a.y += v.y;
}

// bf16 round-to-nearest-even (prep kernel, off hot path)
__device__ __forceinline__ unsigned short bf16_rne(float f) {
    unsigned int u = __float_as_uint(f);
    u += 0x7FFFu + ((u >> 16) & 1u);
    return (unsigned short)(u >> 16);
}

// pack two f32 -> bf16x2 (round-half-up: 2 ops/value, ~RNE accuracy)
__device__ __forceinline__ unsigned int bf16_pack2(float f0, float f1) {
    unsigned int u0 = __float_as_uint(f0) + 0x8000u;
    unsigned int u1 = __float_as_uint(f1) + 0x8000u;
    return (u0 >> 16) | (u1 & 0xFFFF0000u);
}

// Prep: W1 [768][384] f32 -> W1T [384][768] bf16 (RNE). 384 blocks x 768 thr.
// Reads are L2-resident (1.18 MB); writes coalesced.
__global__ __launch_bounds__(768)
void prep_w1t_kernel(const float* __restrict__ W1, unsigned short* __restrict__ W1T) {
    const int c = blockIdx.x;     // 0..383
    const int k = threadIdx.x;    // 0..767
    W1T[c * 768 + k] = bf16_rne(W1[(size_t)k * 384 + c]);
}

// Kernel 0: precompute span boundaries (independent parallel searches).
__global__ __launch_bounds__(192)
void bounds_kernel(const int* __restrict__ seg, int* __restrict__ bounds) {
    const int b = blockIdx.x;
    const int s = threadIdx.x;
    if (s <= SMAX)
        bounds[b * (SMAX + 1) + s] = lower_bound_i(seg + b * TOK, TOK, s);
}

// Fused kernel: phase A = R10 segment sums, stored as bf16 into padded LDS
// A_bf [16 rows][776 bf16] (rows 8-15 zero-padding for the 16x16 MFMA M-dim;
// row stride 1552 B = 97*16 -> 4-bank stagger, ~2-way conflicts = free).
// Layer1 = mfma_f32_16x16x32_bf16: waves 0-11, 2 N-tiles each (24 tiles x 16
// cols = 384), 24 K-steps. a_frag: lane row = l&15, k contiguous (l>>4)*8+e
// via ds_read_b128 — contiguous-k is valid because A and B use the SAME slot
// packing (dot-product is invariant under a shared k-slot bijection).
// b_frag: 16 B global load from W1T (col = l&15). C/D per m89-verified map:
// col = lane&15, row = (lane>>4)*4 + reg; pad rows 8-15 discarded.
// Layer2/3: fp32 k-split identical to R10.
__global__ __launch_bounds__(1024)
void fused_kernel(const float* __restrict__ hidden,
                  const int* __restrict__ bounds,
                  const unsigned short* __restrict__ W1T, const float* __restrict__ b1,
                  const float* __restrict__ W2, const float* __restrict__ b2,
                  const float* __restrict__ W3, const float* __restrict__ b3,
                  float* __restrict__ out) {
    __shared__ __align__(16) unsigned int A_bf32[16 * 388]; // 16 rows x 776 bf16 = 24.8 KB
    __shared__ __align__(16) float X1[BM * 384];            // 12 KB
    __shared__ __align__(16) float X2[BM * 128];            //  4 KB
    __shared__ __align__(16) float P2[8 * BM * 128];        // 32 KB

    const int tid  = threadIdx.x;
    const int row0 = blockIdx.x * BM;
    const int b    = row0 / SMAX;
    const int s0   = row0 % SMAX;
    const int grp  = tid >> 7;    // 0..7
    const int lane = tid & 127;   // owns cols lane*6 .. lane*6+5

    // zero the padding rows 8-15 (read as A rows by MFMA; must be 0)
    for (int i = tid; i < 8 * 388; i += 1024)
        A_bf32[8 * 388 + i] = 0u;

    // ================= phase A: segment sums (R10) -> A_bf =================
    {
        const int lo = bounds[b * (SMAX + 1) + s0 + grp];
        const int hi = bounds[b * (SMAX + 1) + s0 + grp + 1];

        const float2* __restrict__ hp =
            reinterpret_cast<const float2*>(hidden + (size_t)b * TOK * DIM) + lane * 3;

        float2 a0 = make_float2(0.f, 0.f);
        float2 a1 = make_float2(0.f, 0.f);
        float2 a2 = make_float2(0.f, 0.f);

        int t = lo;
        for (; t + 12 <= hi; t += 12) {
            float2 v0[12], v1[12], v2[12];
            #pragma unroll
            for (int u = 0; u < 12; ++u) {
                const float2* p = hp + (size_t)(t + u) * 384;
                v0[u] = p[0]; v1[u] = p[1]; v2[u] = p[2];
            }
            #pragma unroll
            for (int u = 0; u < 12; ++u) {
                f2acc(a0, v0[u]); f2acc(a1, v1[u]); f2acc(a2, v2[u]);
            }
        }
        for (; t + 4 <= hi; t += 4) {
            float2 v0[4], v1[4], v2[4];
            #pragma unroll
            for (int u = 0; u < 4; ++u) {
                const float2* p = hp + (size_t)(t + u) * 384;
                v0[u] = p[0]; v1[u] = p[1]; v2[u] = p[2];
            }
            #pragma unroll
            for (int u = 0; u < 4; ++u) {
                f2acc(a0, v0[u]); f2acc(a1, v1[u]); f2acc(a2, v2[u]);
            }
        }
        for (; t < hi; ++t) {
            const float2* p = hp + (size_t)t * 384;
            f2acc(a0, p[0]); f2acc(a1, p[1]); f2acc(a2, p[2]);
        }

        // store as bf16x2: row grp, u32 slots lane*3 .. +2
        const int base = grp * 388 + lane * 3;
        A_bf32[base + 0] = bf16_pack2(a0.x, a0.y);
        A_bf32[base + 1] = bf16_pack2(a1.x, a1.y);
        A_bf32[base + 2] = bf16_pack2(a2.x, a2.y);
    }
    __syncthreads();

    // ================= layer 1: MFMA =================
    {
        const int wid  = tid >> 6;    // wave 0..15
        const int l    = tid & 63;
        const int lrow = l & 15;      // A row / D col
        const int lg   = l >> 4;      // k-group 0..3

        if (wid < 12) {
            const int n0 = wid * 32;          // col base of N-tile 2*wid
            const int n1 = n0 + 16;           // col base of N-tile 2*wid+1
            f32x4 acc0 = {0.f, 0.f, 0.f, 0.f};
            f32x4 acc1 = {0.f, 0.f, 0.f, 0.f};

            // a_frag u32 index: (lrow*1552 + ks*64 + lg*16)/4
            const unsigned int* abase = &A_bf32[lrow * 388 + lg * 4];
            const unsigned short* w0p = W1T + (size_t)(n0 + lrow) * 768 + lg * 8;
            const unsigned short* w1p = W1T + (size_t)(n1 + lrow) * 768 + lg * 8;

            for (int ks = 0; ks < 24; ++ks) {
                s16x8 af = *reinterpret_cast<const s16x8*>(abase + ks * 16);
                s16x8 bf0 = *reinterpret_cast<const s16x8*>(w0p + ks * 32);
                s16x8 bf1 = *reinterpret_cast<const s16x8*>(w1p + ks * 32);
                acc0 = __builtin_amdgcn_mfma_f32_16x16x32_bf16(af, bf0, acc0, 0, 0, 0);
                acc1 = __builtin_amdgcn_mfma_f32_16x16x32_bf16(af, bf1, acc1, 0, 0, 0);
            }

            if (lg < 2) {   // rows 0..7 real; lg 2,3 hold pad rows 8-15
                const int c0 = n0 + lrow;
                const int c1c = n1 + lrow;
                const float bb0 = b1[c0];
                const float bb1 = b1[c1c];
                #pragma unroll
                for (int r4 = 0; r4 < 4; ++r4) {
                    const int row = lg * 4 + r4;
                    const float v0 = acc0[r4] + bb0;
                    const float v1 = acc1[r4] + bb1;
                    X1[row * 384 + c0]  = v0 > 0.f ? v0 : 0.f;
                    X1[row * 384 + c1c] = v1 > 0.f ? v1 : 0.f;
                }
            }
        }
    }
    __syncthreads();

    // ================= layer 2: fp32 k-split (R10) =================
    const int c1 = lane;          // weight column within 128-group
    const int kg = grp;           // k-slice group 0..7
    {
        float acc2[BM];
        #pragma unroll
        for (int r = 0; r < BM; ++r) acc2[r] = 0.f;

        const int k0 = kg * 48;
        for (int k = k0; k < k0 + 48; k += 4) {
            float4 x[BM];
            #pragma unroll
            for (int r = 0; r < BM; ++r)
                x[r] = *reinterpret_cast<const float4*>(&X1[r * 384 + k]);
            #pragma unroll
            for (int kk = 0; kk < 4; ++kk) {
                const float w = W2[(size_t)(k + kk) * 128 + c1];
                #pragma unroll
                for (int r = 0; r < BM; ++r)
                    acc2[r] = fmaf(f4get(x[r], kk), w, acc2[r]);
            }
        }
        #pragma unroll
        for (int r = 0; r < BM; ++r)
            P2[(kg * BM + r) * 128 + c1] = acc2[r];
    }
    __syncthreads();

    // ---- reduce partials -> X2 (bias + relu), one output per thread ----
    {
        const int row = grp;
        const int col = c1;
        float s = b2[col];
        #pragma unroll
        for (int g = 0; g < 8; ++g)
            s += P2[(g * BM + row) * 128 + col];
        X2[row * 128 + col] = s > 0.f ? s : 0.f;
    }
    __syncthreads();

    // ---- layer 3: 16 outputs ----
    if (tid < BM * 2) {
        const int r = tid >> 1;
        const int c = tid & 1;
        float sacc = 0.f;
        #pragma unroll 8
        for (int k = 0; k < 128; ++k)
            sacc = fmaf(X2[r * 128 + k], W3[k * 2 + c], sacc);
        out[(row0 + r) * 2 + c] = sacc + b3[c];
    }
}

extern "C" void kernel_launch(void* const* d_in, const int* in_sizes, int n_in,
                              void* d_out, int out_size, void* d_ws, size_t ws_size,
                              hipStream_t stream) {
    const float* hidden = (const float*)d_in[0];
    const int*   seg    = (const int*)d_in[1];
    const float* W1     = (const float*)d_in[2];
    const float* b1     = (const float*)d_in[3];
    const float* W2     = (const float*)d_in[4];
    const float* b2     = (const float*)d_in[5];
    const float* W3     = (const float*)d_in[6];
    const float* b3     = (const float*)d_in[7];
    float* out = (float*)d_out;

    int* bounds = (int*)d_ws;                                    // 8.3 KB
    unsigned short* W1T = (unsigned short*)((char*)d_ws + 16384); // 576 KB

    prep_w1t_kernel<<<384, 768, 0, stream>>>(W1, W1T);
    bounds_kernel<<<BATCH, 192, 0, stream>>>(seg, bounds);
    fused_kernel<<<(BATCH * SMAX) / BM, 1024, 0, stream>>>(
        hidden, bounds, W1T, b1, W2, b2, W3, b3, out);
}

// Round 16
// 65.565 us; speedup vs baseline: 1.1215x; 1.0069x over previous
//
#include <hip/hip_runtime.h>

#define BATCH 16
#define TOK   4096
#define DIM   768
#define SMAX  128
#define BM    8     // segments (= MLP rows) per block

typedef float f32x4 __attribute__((ext_vector_type(4)));
typedef short s16x8 __attribute__((ext_vector_type(8)));

__device__ __forceinline__ int lower_bound_i(const int* __restrict__ a, int n, int v) {
    int lo = 0, hi = n;
    while (lo < hi) {
        int m = (lo + hi) >> 1;
        if (a[m] < v) lo = m + 1; else hi = m;
    }
    return lo;
}

__device__ __forceinline__ float f4get(const float4& v, int k) {
    switch (k) {
        case 0: return v.x;
        case 1: return v.y;
        case 2: return v.z;
        default: return v.w;
    }
}

__device__ __forceinline__ void f4acc(float4& a, const float4& v) {
    a.x += v.x; a.y += v.y; a.z += v.z; a.w += v.w;
}

// bf16 round-to-nearest-even (prep kernel, off hot path)
__device__ __forceinline__ unsigned short bf16_rne(float f) {
    unsigned int u = __float_as_uint(f);
    u += 0x7FFFu + ((u >> 16) & 1u);
    return (unsigned short)(u >> 16);
}

// pack two f32 -> bf16x2 (round-half-up)
__device__ __forceinline__ unsigned int bf16_pack2(float f0, float f1) {
    unsigned int u0 = __float_as_uint(f0) + 0x8000u;
    unsigned int u1 = __float_as_uint(f1) + 0x8000u;
    return (u0 >> 16) | (u1 & 0xFFFF0000u);
}

// Prep: W1 [768][384] f32 -> W1T [384][768] bf16 (RNE).
__global__ __launch_bounds__(768)
void prep_w1t_kernel(const float* __restrict__ W1, unsigned short* __restrict__ W1T) {
    const int c = blockIdx.x;     // 0..383
    const int k = threadIdx.x;    // 0..767
    W1T[c * 768 + k] = bf16_rne(W1[(size_t)k * 384 + c]);
}

// Kernel 0: precompute span boundaries (independent parallel searches).
__global__ __launch_bounds__(192)
void bounds_kernel(const int* __restrict__ seg, int* __restrict__ bounds) {
    const int b = blockIdx.x;
    const int s = threadIdx.x;
    if (s <= SMAX)
        bounds[b * (SMAX + 1) + s] = lower_bound_i(seg + b * TOK, TOK, s);
}

// Fused kernel. Phase A v2: per segment group (128 thr), two 64-lane halves
// split tokens by parity (h sums lo+h, lo+h+2, ...); lane owns 12 consecutive
// cols = 3 float4 (16 B/lane). h=1 partials via LDS scratch (P2 alias), h=0
// combines (fixed order) and packs bf16 into padded A_bf [16][776].
// Layer1 = mfma_f32_16x16x32_bf16 (R14, verified: absmax 0.031).
// Layer2/3: fp32 k-split (R10).
__global__ __launch_bounds__(1024)
void fused_kernel(const float* __restrict__ hidden,
                  const int* __restrict__ bounds,
                  const unsigned short* __restrict__ W1T, const float* __restrict__ b1,
                  const float* __restrict__ W2, const float* __restrict__ b2,
                  const float* __restrict__ W3, const float* __restrict__ b3,
                  float* __restrict__ out) {
    __shared__ __align__(16) unsigned int A_bf32[16 * 388]; // 16 rows x 776 bf16 = 24.8 KB
    __shared__ __align__(16) float X1[BM * 384];            // 12 KB
    __shared__ __align__(16) float X2[BM * 128];            //  4 KB
    __shared__ __align__(16) float P2[8 * BM * 128];        // 32 KB (phaseA scratch alias)

    const int tid  = threadIdx.x;
    const int row0 = blockIdx.x * BM;
    const int b    = row0 / SMAX;
    const int s0   = row0 % SMAX;
    const int grp  = tid >> 7;    // segment 0..7
    const int lane = tid & 127;
    const int h    = lane >> 6;   // token-parity half 0/1
    const int l6   = lane & 63;   // owns cols l6*12 .. l6*12+11

    // zero the padding rows 8-15 (read as A rows by MFMA; must be 0)
    for (int i = tid; i < 8 * 388; i += 1024)
        A_bf32[8 * 388 + i] = 0u;

    // ================= phase A: parity-split segment sums =================
    {
        const int lo = bounds[b * (SMAX + 1) + s0 + grp];
        const int hi = bounds[b * (SMAX + 1) + s0 + grp + 1];

        // float4 view: row has 192 float4; this lane's base = l6*3
        const float4* __restrict__ hp =
            reinterpret_cast<const float4*>(hidden + (size_t)b * TOK * DIM) + l6 * 3;

        float4 a0 = make_float4(0.f, 0.f, 0.f, 0.f);
        float4 a1 = make_float4(0.f, 0.f, 0.f, 0.f);
        float4 a2 = make_float4(0.f, 0.f, 0.f, 0.f);

        int t = lo + h;
        // 4 token-pairs deep: 12 independent float4 loads in flight
        for (; t + 8 <= hi; t += 8) {
            float4 v0[4], v1[4], v2[4];
            #pragma unroll
            for (int u = 0; u < 4; ++u) {
                const float4* p = hp + (size_t)(t + 2 * u) * 192;
                v0[u] = p[0]; v1[u] = p[1]; v2[u] = p[2];
            }
            #pragma unroll
            for (int u = 0; u < 4; ++u) {
                f4acc(a0, v0[u]); f4acc(a1, v1[u]); f4acc(a2, v2[u]);
            }
        }
        for (; t < hi; t += 2) {
            const float4* p = hp + (size_t)t * 192;
            f4acc(a0, p[0]); f4acc(a1, p[1]); f4acc(a2, p[2]);
        }

        // h=1 partials -> LDS scratch; h=0 combines (fixed order) and packs
        float4* scr = reinterpret_cast<float4*>(P2) + (grp * 64 + l6) * 3;
        if (h == 1) {
            scr[0] = a0; scr[1] = a1; scr[2] = a2;
        }
        __syncthreads();
        if (h == 0) {
            f4acc(a0, scr[0]); f4acc(a1, scr[1]); f4acc(a2, scr[2]);
            const int base = grp * 388 + l6 * 6;
            A_bf32[base + 0] = bf16_pack2(a0.x, a0.y);
            A_bf32[base + 1] = bf16_pack2(a0.z, a0.w);
            A_bf32[base + 2] = bf16_pack2(a1.x, a1.y);
            A_bf32[base + 3] = bf16_pack2(a1.z, a1.w);
            A_bf32[base + 4] = bf16_pack2(a2.x, a2.y);
            A_bf32[base + 5] = bf16_pack2(a2.z, a2.w);
        }
    }
    __syncthreads();

    // ================= layer 1: MFMA (R14, verified) =================
    {
        const int wid  = tid >> 6;    // wave 0..15
        const int l    = tid & 63;
        const int lrow = l & 15;      // A row / D col
        const int lg   = l >> 4;      // k-group 0..3

        if (wid < 12) {
            const int n0 = wid * 32;
            const int n1 = n0 + 16;
            f32x4 acc0 = {0.f, 0.f, 0.f, 0.f};
            f32x4 acc1 = {0.f, 0.f, 0.f, 0.f};

            const unsigned int* abase = &A_bf32[lrow * 388 + lg * 4];
            const unsigned short* w0p = W1T + (size_t)(n0 + lrow) * 768 + lg * 8;
            const unsigned short* w1p = W1T + (size_t)(n1 + lrow) * 768 + lg * 8;

            for (int ks = 0; ks < 24; ++ks) {
                s16x8 af  = *reinterpret_cast<const s16x8*>(abase + ks * 16);
                s16x8 bf0 = *reinterpret_cast<const s16x8*>(w0p + ks * 32);
                s16x8 bf1 = *reinterpret_cast<const s16x8*>(w1p + ks * 32);
                acc0 = __builtin_amdgcn_mfma_f32_16x16x32_bf16(af, bf0, acc0, 0, 0, 0);
                acc1 = __builtin_amdgcn_mfma_f32_16x16x32_bf16(af, bf1, acc1, 0, 0, 0);
            }

            if (lg < 2) {   // rows 0..7 real; lg 2,3 hold pad rows 8-15
                const int c0  = n0 + lrow;
                const int c1c = n1 + lrow;
                const float bb0 = b1[c0];
                const float bb1 = b1[c1c];
                #pragma unroll
                for (int r4 = 0; r4 < 4; ++r4) {
                    const int row = lg * 4 + r4;
                    const float v0 = acc0[r4] + bb0;
                    const float v1 = acc1[r4] + bb1;
                    X1[row * 384 + c0]  = v0 > 0.f ? v0 : 0.f;
                    X1[row * 384 + c1c] = v1 > 0.f ? v1 : 0.f;
                }
            }
        }
    }
    __syncthreads();

    // ================= layer 2: fp32 k-split (R10) =================
    const int c1 = lane;          // weight column within 128-group
    const int kg = grp;           // k-slice group 0..7
    {
        float acc2[BM];
        #pragma unroll
        for (int r = 0; r < BM; ++r) acc2[r] = 0.f;

        const int k0 = kg * 48;
        for (int k = k0; k < k0 + 48; k += 4) {
            float4 x[BM];
            #pragma unroll
            for (int r = 0; r < BM; ++r)
                x[r] = *reinterpret_cast<const float4*>(&X1[r * 384 + k]);
            #pragma unroll
            for (int kk = 0; kk < 4; ++kk) {
                const float w = W2[(size_t)(k + kk) * 128 + c1];
                #pragma unroll
                for (int r = 0; r < BM; ++r)
                    acc2[r] = fmaf(f4get(x[r], kk), w, acc2[r]);
            }
        }
        #pragma unroll
        for (int r = 0; r < BM; ++r)
            P2[(kg * BM + r) * 128 + c1] = acc2[r];
    }
    __syncthreads();

    // ---- reduce partials -> X2 (bias + relu) ----
    {
        const int row = grp;
        const int col = c1;
        float s = b2[col];
        #pragma unroll
        for (int g = 0; g < 8; ++g)
            s += P2[(g * BM + row) * 128 + col];
        X2[row * 128 + col] = s > 0.f ? s : 0.f;
    }
    __syncthreads();

    // ---- layer 3: 16 outputs ----
    if (tid < BM * 2) {
        const int r = tid >> 1;
        const int c = tid & 1;
        float sacc = 0.f;
        #pragma unroll 8
        for (int k = 0; k < 128; ++k)
            sacc = fmaf(X2[r * 128 + k], W3[k * 2 + c], sacc);
        out[(row0 + r) * 2 + c] = sacc + b3[c];
    }
}

extern "C" void kernel_launch(void* const* d_in, const int* in_sizes, int n_in,
                              void* d_out, int out_size, void* d_ws, size_t ws_size,
                              hipStream_t stream) {
    const float* hidden = (const float*)d_in[0];
    const int*   seg    = (const int*)d_in[1];
    const float* W1     = (const float*)d_in[2];
    const float* b1     = (const float*)d_in[3];
    const float* W2     = (const float*)d_in[4];
    const float* b2     = (const float*)d_in[5];
    const float* W3     = (const float*)d_in[6];
    const float* b3     = (const float*)d_in[7];
    float* out = (float*)d_out;

    int* bounds = (int*)d_ws;                                     // 8.3 KB
    unsigned short* W1T = (unsigned short*)((char*)d_ws + 16384); // 576 KB

    prep_w1t_kernel<<<384, 768, 0, stream>>>(W1, W1T);
    bounds_kernel<<<BATCH, 192, 0, stream>>>(seg, bounds);
    fused_kernel<<<(BATCH * SMAX) / BM, 1024, 0, stream>>>(
        hidden, bounds, W1T, b1, W2, b2, W3, b3, out);
}